// Round 7
// baseline (84.858 us; speedup 1.0000x reference)
//
#include <hip/hip_runtime.h>

static constexpr int NSIDE = 48;
static constexpr int NVOX  = NSIDE * NSIDE * NSIDE;   // 110592
static constexpr float SCALE = 0.041875863808787856f; // ONE_OVER_DIFF_TOT * DIFF_Q
static constexpr int NDIR  = 13;                      // canonical half of the 26 offsets
static constexpr int VOX_PER_BLOCK = 64;              // 2 waves x 32 voxels
static constexpr int NBLOCKS = NVOX / VOX_PER_BLOCK;  // 1728

typedef _Float16 f16x8 __attribute__((ext_vector_type(8)));
typedef float    f32x16 __attribute__((ext_vector_type(16)));

// Canonical directions (first nonzero component positive).
__device__ __constant__ int g_ox[NDIR] = { 1, 0, 0,  1, 1, 1, 1, 0, 0,  1, 1, 1, 1 };
__device__ __constant__ int g_oy[NDIR] = { 0, 1, 0,  1,-1, 0, 0, 1, 1,  1, 1,-1,-1 };
__device__ __constant__ int g_oz[NDIR] = { 0, 0, 1,  0, 0, 1,-1, 1,-1,  1,-1, 1,-1 };
__device__ __constant__ float g_dinv[NDIR] = {
    1.f, 1.f, 1.f,
    0.70710678118654752f, 0.70710678118654752f, 0.70710678118654752f,
    0.70710678118654752f, 0.70710678118654752f, 0.70710678118654752f,
    0.57735026918962576f, 0.57735026918962576f, 0.57735026918962576f, 0.57735026918962576f };

// Full 26-neighbor tables for the fallback single-pass kernel.
__device__ __constant__ int c_ox[26] = { 1,-1, 0, 0, 0, 0,
                                         1,-1, 1,-1, 1,-1, 1,-1, 0, 0, 0, 0,
                                         1, 1, 1, 1,-1,-1,-1,-1 };
__device__ __constant__ int c_oy[26] = { 0, 0, 1,-1, 0, 0,
                                         1, 1,-1,-1, 0, 0, 0, 0, 1,-1, 1,-1,
                                         1, 1,-1,-1, 1, 1,-1,-1 };
__device__ __constant__ int c_oz[26] = { 0, 0, 0, 0, 1,-1,
                                         0, 0, 0, 0, 1, 1,-1,-1, 1, 1,-1,-1,
                                         1,-1, 1,-1, 1,-1, 1,-1 };
__device__ __constant__ float c_dinv[26] = {
    1.f, 1.f, 1.f, 1.f, 1.f, 1.f,
    0.70710678118654752f, 0.70710678118654752f, 0.70710678118654752f, 0.70710678118654752f,
    0.70710678118654752f, 0.70710678118654752f, 0.70710678118654752f, 0.70710678118654752f,
    0.70710678118654752f, 0.70710678118654752f, 0.70710678118654752f, 0.70710678118654752f,
    0.57735026918962576f, 0.57735026918962576f, 0.57735026918962576f, 0.57735026918962576f,
    0.57735026918962576f, 0.57735026918962576f, 0.57735026918962576f, 0.57735026918962576f };

__device__ __forceinline__ float fast_tanh(float x) {
    float e = __builtin_amdgcn_exp2f(x * 2.8853900817779268f);
    float r = __builtin_amdgcn_rcpf(e + 1.0f);
    return fmaf(-2.0f, r, 1.0f);
}

// Pade[5/4] tanh on an (eval-a, eval-b) duo sharing ONE rcp:
//   tanh x ~ x(945+105u+u^2)/(945+420u+15u^2), u=x^2, clamp to [-1,1].
// Max |err| ~1.3e-3; raw value stays >=1 past the x~3.7 crossing, so the
// output clamp is safe for all |x|.
__device__ __forceinline__ void pade_tanh_duo(float xa, float xb, float& ta, float& tb) {
    const float ua = xa * xa, ub = xb * xb;
    const float na = fmaf(ua, ua + 105.0f, 945.0f);
    const float nb = fmaf(ub, ub + 105.0f, 945.0f);
    const float ea = fmaf(ua, fmaf(ua, 15.0f, 420.0f), 945.0f);
    const float eb = fmaf(ub, fmaf(ub, 15.0f, 420.0f), 945.0f);
    const float R  = __builtin_amdgcn_rcpf(ea * eb);   // 1 trans for 2 tanh
    ta = (xa * na) * (eb * R);
    tb = (xb * nb) * (ea * R);
    ta = fminf(1.0f, fmaxf(-1.0f, ta));
    tb = fminf(1.0f, fmaxf(-1.0f, tb));
}

// LDS weight layout (floats):
//  W0:[0,64) b0:[64,80) W1:[80,336) b1:[336,352) W2:[352,608) b2:[608,624)
//  W3:[624,880) b3:[880,896) Wout:[896,912) bout:[912]

// sigma(g,p): k-index owned by lane-group g, fragment slot p. Same convention
// builds A (weights), bias vectors and B (inputs); D-chaining reproduces it,
// so any mismatch vs the HW's internal order cancels (verified on HW in R5).
#define SIG(G, P) (((P) < 4) ? 4 * (G) + (P) : 8 + 4 * (G) + ((P) - 4))

// ---------------------------------------------------------------------------
// MFMA flux kernel, k-loop version. Each block: 128 threads = 2 waves, each
// wave owns 32 voxels and loops over all 13 directions, reusing the
// register-resident weight fragments (setup cost amortized 13x). Hidden
// layers on v_mfma_f32_32x32x16_f16 with C=0 and scalar bias-adds before the
// Pade activation. Layer 0 (4->16) on VALU from broadcast LDS reads.
__global__ __launch_bounds__(128)
void flux_mfma_kernel(const float* __restrict__ q,
                      const float* __restrict__ W0, const float* __restrict__ b0,
                      const float* __restrict__ W1, const float* __restrict__ b1,
                      const float* __restrict__ W2, const float* __restrict__ b2,
                      const float* __restrict__ W3, const float* __restrict__ b3,
                      const float* __restrict__ Wout, const float* __restrict__ bout,
                      float* __restrict__ ws)
{
    __shared__ __align__(16) float sw[916];
    {
        const int t_ = threadIdx.x;                       // 0..127
        if (t_ <  64) sw[      t_] = W0[t_];
        if (t_ <  16) sw[ 64 + t_] = b0[t_];
                      sw[ 80 + t_] = W1[t_];
                      sw[208 + t_] = W1[128 + t_];
        if (t_ <  16) sw[336 + t_] = b1[t_];
                      sw[352 + t_] = W2[t_];
                      sw[480 + t_] = W2[128 + t_];
        if (t_ <  16) sw[608 + t_] = b2[t_];
                      sw[624 + t_] = W3[t_];
                      sw[752 + t_] = W3[128 + t_];
        if (t_ <  16) sw[880 + t_] = b3[t_];
        if (t_ <  16) sw[896 + t_] = Wout[t_];
        if (t_ ==  0) sw[912]     = bout[0];
        __syncthreads();
    }

    const int lane = threadIdx.x & 63;
    const int wv   = threadIdx.x >> 6;                    // 0/1
    const int g    = lane >> 5;                           // feature-half 0/1
    const int vox  = blockIdx.x * VOX_PER_BLOCK + wv * 32 + (lane & 31);

    const int z = vox % NSIDE;
    const int y = (vox / NSIDE) % NSIDE;
    const int x = vox / (NSIDE * NSIDE);
    const int xp = (x == NSIDE - 1) ? 0 : x + 1;
    const int ym = (y == 0) ? NSIDE - 1 : y - 1;
    const int yp = (y == NSIDE - 1) ? 0 : y + 1;
    const int zm = (z == 0) ? NSIDE - 1 : z - 1;
    const int zp = (z == NSIDE - 1) ? 0 : z + 1;

    const float2 own = reinterpret_cast<const float2*>(q)[vox];
    const float o0 = own.x, o1 = own.y;

    // --- loop-invariant fragments (registers for the whole k-loop) ---
    const int wr = (lane & 15) * 16;      // A-rows >=16 produce garbage only in
                                          // D regs p>=8, which are never read.
    f16x8 aw1, aw2, aw3;
    float bs1[8], bs2[8], bs3[8], woutv[8];
    #pragma unroll
    for (int p = 0; p < 8; ++p) {
        const int kk = SIG(g, p);
        aw1[p] = (_Float16)sw[ 80 + wr + kk];
        aw2[p] = (_Float16)sw[352 + wr + kk];
        aw3[p] = (_Float16)sw[624 + wr + kk];
        bs1[p] = sw[336 + kk];
        bs2[p] = sw[608 + kk];
        bs3[p] = sw[880 + kk];
        woutv[p] = sw[896 + kk];
    }
    f32x16 zc;
    #pragma unroll
    for (int p = 0; p < 16; ++p) zc[p] = 0.0f;

    #pragma unroll 1
    for (int k = 0; k < NDIR; ++k) {
        // Stop cross-iteration LICM of in-loop LDS reads (R1/R2 spill lesson);
        // register-resident fragments above are unaffected.
        asm volatile("" ::: "memory");

        const int ox = g_ox[k], oy = g_oy[k], oz = g_oz[k];
        const int nx = ox ? xp : x;                       // ox in {0,1}
        const int ny = (oy > 0) ? yp : ((oy < 0) ? ym : y);
        const int nz = (oz > 0) ? zp : ((oz < 0) ? zm : z);
        const float2 nbq = reinterpret_cast<const float2*>(q)[(nx * NSIDE + ny) * NSIDE + nz];
        const float n0 = nbq.x, n1 = nbq.y;

        // --- layer 0 (4 -> 16) on VALU, broadcast LDS float4 reads ---
        f16x8 ba, bb;
        #pragma unroll
        for (int p = 0; p < 8; ++p) {
            const int f = SIG(g, p);
            const float4 w = *reinterpret_cast<const float4*>(&sw[f * 4]);
            const float bbias = sw[64 + f];
            float pa = fmaf(w.x, o0, fmaf(w.y, o1, fmaf(w.z, n0, fmaf(w.w, n1, bbias))));
            float pb = fmaf(w.x, n0, fmaf(w.y, n1, fmaf(w.z, o0, fmaf(w.w, o1, bbias))));
            float ta, tb;
            pade_tanh_duo(pa, pb, ta, tb);
            ba[p] = (_Float16)ta;
            bb[p] = (_Float16)tb;
        }

        // --- hidden layers 1..3 on MFMA (C=0, bias added pre-activation) ---
        f32x16 da, db;
        da = __builtin_amdgcn_mfma_f32_32x32x16_f16(aw1, ba, zc, 0, 0, 0);
        db = __builtin_amdgcn_mfma_f32_32x32x16_f16(aw1, bb, zc, 0, 0, 0);
        #pragma unroll
        for (int p = 0; p < 8; ++p) {
            float ta, tb;
            pade_tanh_duo(da[p] + bs1[p], db[p] + bs1[p], ta, tb);
            ba[p] = (_Float16)ta;
            bb[p] = (_Float16)tb;
        }
        da = __builtin_amdgcn_mfma_f32_32x32x16_f16(aw2, ba, zc, 0, 0, 0);
        db = __builtin_amdgcn_mfma_f32_32x32x16_f16(aw2, bb, zc, 0, 0, 0);
        #pragma unroll
        for (int p = 0; p < 8; ++p) {
            float ta, tb;
            pade_tanh_duo(da[p] + bs2[p], db[p] + bs2[p], ta, tb);
            ba[p] = (_Float16)ta;
            bb[p] = (_Float16)tb;
        }
        da = __builtin_amdgcn_mfma_f32_32x32x16_f16(aw3, ba, zc, 0, 0, 0);
        db = __builtin_amdgcn_mfma_f32_32x32x16_f16(aw3, bb, zc, 0, 0, 0);

        // --- output head (16 -> 1): Pade tanh then partial dot; complement
        //     from lane^32. bout cancels in (oa - ob).
        float pa = 0.0f, pb = 0.0f;
        #pragma unroll
        for (int p = 0; p < 8; ++p) {
            float ta, tb;
            pade_tanh_duo(da[p] + bs3[p], db[p] + bs3[p], ta, tb);
            pa = fmaf(ta, woutv[p], pa);
            pb = fmaf(tb, woutv[p], pb);
        }
        pa += __shfl_xor(pa, 32);
        pb += __shfl_xor(pb, 32);

        const float tr  = fast_tanh(pa - pb);   // exact tanh for the output
        const float fac = (tr < 0.0f) ? o0 : n0;
        if (lane < 32)
            ws[k * NVOX + vox] = tr * fac * g_dinv[k];
    }
}

// ---------------------------------------------------------------------------
// Pass 2: per voxel u, total = sum_k ( f[k][u] - f[k][u - d_k] ).
__global__ __launch_bounds__(256)
void gather_kernel(const float* __restrict__ q,
                   const float* __restrict__ ws,
                   float* __restrict__ out)
{
    const int vox = blockIdx.x * 256 + threadIdx.x;

    const int z = vox % NSIDE;
    const int y = (vox / NSIDE) % NSIDE;
    const int x = vox / (NSIDE * NSIDE);
    const int xm = (x == 0) ? NSIDE - 1 : x - 1;
    const int ym = (y == 0) ? NSIDE - 1 : y - 1;
    const int yp = (y == NSIDE - 1) ? 0 : y + 1;
    const int zm = (z == 0) ? NSIDE - 1 : z - 1;
    const int zp = (z == NSIDE - 1) ? 0 : z + 1;

    float s = 0.0f;
    #pragma unroll
    for (int k = 0; k < NDIR; ++k) {
        const int px = g_ox[k] ? xm : x;
        const int py = (g_oy[k] > 0) ? ym : ((g_oy[k] < 0) ? yp : y);
        const int pz = (g_oz[k] > 0) ? zm : ((g_oz[k] < 0) ? zp : z);
        s += ws[k * NVOX + vox];
        s -= ws[k * NVOX + (px * NSIDE + py) * NSIDE + pz];
    }

    const float2 own = reinterpret_cast<const float2*>(q)[vox];
    float2 r;
    r.x = fmaf(s, SCALE, own.x);
    r.y = own.y;
    reinterpret_cast<float2*>(out)[vox] = r;
}

// ---------------------------------------------------------------------------
// Fallback: Round-3 single-pass scalar kernel (used only if ws is too small).
#define STAGE_WEIGHTS_256()                                                    \
    __shared__ __align__(16) float sw[916];                                    \
    {                                                                          \
        const int t_ = threadIdx.x;                                            \
        if (t_ <  64) sw[      t_] = W0[t_];                                   \
        if (t_ <  16) sw[ 64 + t_] = b0[t_];                                   \
                      sw[ 80 + t_] = W1[t_];                                   \
        if (t_ <  16) sw[336 + t_] = b1[t_];                                   \
                      sw[352 + t_] = W2[t_];                                   \
        if (t_ <  16) sw[608 + t_] = b2[t_];                                   \
                      sw[624 + t_] = W3[t_];                                   \
        if (t_ <  16) sw[880 + t_] = b3[t_];                                   \
        if (t_ <  16) sw[896 + t_] = Wout[t_];                                 \
        if (t_ ==  0) sw[912]     = bout[0];                                   \
        __syncthreads();                                                       \
    }

#define LAYER(WB, INA, INB, OUTA, OUTB)                                        \
    {                                                                          \
        _Pragma("unroll")                                                      \
        for (int i = 0; i < 16; ++i) {                                         \
            float aa = sw[(WB) + 256 + i];                                     \
            float ab = aa;                                                     \
            _Pragma("unroll")                                                  \
            for (int kk = 0; kk < 4; ++kk) {                                   \
                const float4 w = *reinterpret_cast<const float4*>(             \
                    &sw[(WB) + i * 16 + kk * 4]);                              \
                aa = fmaf(w.x, INA[4 * kk + 0], aa);                           \
                aa = fmaf(w.y, INA[4 * kk + 1], aa);                           \
                aa = fmaf(w.z, INA[4 * kk + 2], aa);                           \
                aa = fmaf(w.w, INA[4 * kk + 3], aa);                           \
                ab = fmaf(w.x, INB[4 * kk + 0], ab);                           \
                ab = fmaf(w.y, INB[4 * kk + 1], ab);                           \
                ab = fmaf(w.z, INB[4 * kk + 2], ab);                           \
                ab = fmaf(w.w, INB[4 * kk + 3], ab);                           \
            }                                                                  \
            OUTA[i] = fast_tanh(aa);                                           \
            OUTB[i] = fast_tanh(ab);                                           \
        }                                                                      \
    }

__global__ __launch_bounds__(256)
void automaton_kernel(const float* __restrict__ q,
                      const float* __restrict__ W0, const float* __restrict__ b0,
                      const float* __restrict__ W1, const float* __restrict__ b1,
                      const float* __restrict__ W2, const float* __restrict__ b2,
                      const float* __restrict__ W3, const float* __restrict__ b3,
                      const float* __restrict__ Wout, const float* __restrict__ bout,
                      float* __restrict__ out)
{
    STAGE_WEIGHTS_256()

    const int gid  = blockIdx.x * 256 + threadIdx.x;
    const int vox  = gid >> 1;
    const int half = gid & 1;

    const int z = vox % NSIDE;
    const int y = (vox / NSIDE) % NSIDE;
    const int x = vox / (NSIDE * NSIDE);
    const int xm = (x == 0) ? NSIDE - 1 : x - 1;
    const int xp = (x == NSIDE - 1) ? 0 : x + 1;
    const int ym = (y == 0) ? NSIDE - 1 : y - 1;
    const int yp = (y == NSIDE - 1) ? 0 : y + 1;
    const int zm = (z == 0) ? NSIDE - 1 : z - 1;
    const int zp = (z == NSIDE - 1) ? 0 : z + 1;

    const float2 own = reinterpret_cast<const float2*>(q)[vox];
    const float o0 = own.x, o1 = own.y;

    float sum = 0.0f;
    #pragma unroll 1
    for (int k = half * 13; k < half * 13 + 13; ++k) {
        asm volatile("" ::: "memory");   // block cross-iteration LICM of weight loads
        const int ox = c_ox[k], oy = c_oy[k], oz = c_oz[k];
        const int nx = (ox < 0) ? xm : ((ox > 0) ? xp : x);
        const int ny = (oy < 0) ? ym : ((oy > 0) ? yp : y);
        const int nz = (oz < 0) ? zm : ((oz > 0) ? zp : z);
        const float2 nbq = reinterpret_cast<const float2*>(q)[(nx * NSIDE + ny) * NSIDE + nz];
        const float n0 = nbq.x, n1 = nbq.y;

        float ha[16], hb[16], ta[16], tb[16];
        #pragma unroll
        for (int i = 0; i < 16; ++i) {
            const float4 w = *reinterpret_cast<const float4*>(&sw[i * 4]);
            const float bbias = sw[64 + i];
            float pa = fmaf(w.x, o0, fmaf(w.y, o1, fmaf(w.z, n0, fmaf(w.w, n1, bbias))));
            float pb = fmaf(w.x, n0, fmaf(w.y, n1, fmaf(w.z, o0, fmaf(w.w, o1, bbias))));
            ha[i] = fast_tanh(pa);
            hb[i] = fast_tanh(pb);
        }
        LAYER(80,  ha, hb, ta, tb)
        LAYER(352, ta, tb, ha, hb)
        LAYER(624, ha, hb, ta, tb)
        float oa = sw[912], ob = sw[912];
        #pragma unroll
        for (int kk = 0; kk < 4; ++kk) {
            const float4 w = *reinterpret_cast<const float4*>(&sw[896 + kk * 4]);
            oa = fmaf(w.x, ta[4 * kk + 0], oa);
            oa = fmaf(w.y, ta[4 * kk + 1], oa);
            oa = fmaf(w.z, ta[4 * kk + 2], oa);
            oa = fmaf(w.w, ta[4 * kk + 3], oa);
            ob = fmaf(w.x, tb[4 * kk + 0], ob);
            ob = fmaf(w.y, tb[4 * kk + 1], ob);
            ob = fmaf(w.z, tb[4 * kk + 2], ob);
            ob = fmaf(w.w, tb[4 * kk + 3], ob);
        }
        const float tr  = fast_tanh(oa - ob);
        const float fac = (tr < 0.0f) ? o0 : n0;
        sum = fmaf(tr * fac, c_dinv[k], sum);
    }

    sum += __shfl_xor(sum, 1);
    if (half == 0) {
        float2 r;
        r.x = fmaf(sum, SCALE, o0);
        r.y = o1;
        reinterpret_cast<float2*>(out)[vox] = r;
    }
}

extern "C" void kernel_launch(void* const* d_in, const int* in_sizes, int n_in,
                              void* d_out, int out_size, void* d_ws, size_t ws_size,
                              hipStream_t stream) {
    const float* q    = (const float*)d_in[0];
    const float* W0   = (const float*)d_in[1];
    const float* b0   = (const float*)d_in[2];
    const float* W1   = (const float*)d_in[3];
    const float* b1   = (const float*)d_in[4];
    const float* W2   = (const float*)d_in[5];
    const float* b2   = (const float*)d_in[6];
    const float* W3   = (const float*)d_in[7];
    const float* b3   = (const float*)d_in[8];
    const float* Wout = (const float*)d_in[9];
    const float* bout = (const float*)d_in[10];
    float* out = (float*)d_out;

    const size_t ws_needed = (size_t)NDIR * NVOX * sizeof(float);  // 5.75 MB
    if (ws_size >= ws_needed) {
        float* ws = (float*)d_ws;
        flux_mfma_kernel<<<dim3(NBLOCKS), dim3(128), 0, stream>>>(
            q, W0, b0, W1, b1, W2, b2, W3, b3, Wout, bout, ws);
        gather_kernel<<<dim3(NVOX / 256), dim3(256), 0, stream>>>(q, ws, out);
    } else {
        automaton_kernel<<<dim3(NVOX * 2 / 256), dim3(256), 0, stream>>>(
            q, W0, b0, W1, b1, W2, b2, W3, b3, Wout, bout, out);
    }
}

// Round 8
// 68.977 us; speedup vs baseline: 1.2302x; 1.2302x over previous
//
#include <hip/hip_runtime.h>

static constexpr int NSIDE = 48;
static constexpr int NVOX  = NSIDE * NSIDE * NSIDE;   // 110592
static constexpr float SCALE = 0.041875863808787856f; // ONE_OVER_DIFF_TOT * DIFF_Q
static constexpr int NDIR  = 13;                      // canonical half of the 26 offsets
static constexpr int NVOXGRP = NVOX / 32;             // 3456 voxel-groups of 32
static constexpr int NSLICE  = 4;                     // direction slices
static constexpr int FLUX_BLOCKS = NVOXGRP;           // 3456 blocks (4 waves each)

typedef _Float16 f16x8 __attribute__((ext_vector_type(8)));
typedef float    f32x16 __attribute__((ext_vector_type(16)));

// Canonical directions (first nonzero component positive).
__device__ __constant__ int g_ox[NDIR] = { 1, 0, 0,  1, 1, 1, 1, 0, 0,  1, 1, 1, 1 };
__device__ __constant__ int g_oy[NDIR] = { 0, 1, 0,  1,-1, 0, 0, 1, 1,  1, 1,-1,-1 };
__device__ __constant__ int g_oz[NDIR] = { 0, 0, 1,  0, 0, 1,-1, 1,-1,  1,-1, 1,-1 };
__device__ __constant__ float g_dinv[NDIR] = {
    1.f, 1.f, 1.f,
    0.70710678118654752f, 0.70710678118654752f, 0.70710678118654752f,
    0.70710678118654752f, 0.70710678118654752f, 0.70710678118654752f,
    0.57735026918962576f, 0.57735026918962576f, 0.57735026918962576f, 0.57735026918962576f };

// Full 26-neighbor tables for the fallback single-pass kernel.
__device__ __constant__ int c_ox[26] = { 1,-1, 0, 0, 0, 0,
                                         1,-1, 1,-1, 1,-1, 1,-1, 0, 0, 0, 0,
                                         1, 1, 1, 1,-1,-1,-1,-1 };
__device__ __constant__ int c_oy[26] = { 0, 0, 1,-1, 0, 0,
                                         1, 1,-1,-1, 0, 0, 0, 0, 1,-1, 1,-1,
                                         1, 1,-1,-1, 1, 1,-1,-1 };
__device__ __constant__ int c_oz[26] = { 0, 0, 0, 0, 1,-1,
                                         0, 0, 0, 0, 1, 1,-1,-1, 1, 1,-1,-1,
                                         1,-1, 1,-1, 1,-1, 1,-1 };
__device__ __constant__ float c_dinv[26] = {
    1.f, 1.f, 1.f, 1.f, 1.f, 1.f,
    0.70710678118654752f, 0.70710678118654752f, 0.70710678118654752f, 0.70710678118654752f,
    0.70710678118654752f, 0.70710678118654752f, 0.70710678118654752f, 0.70710678118654752f,
    0.70710678118654752f, 0.70710678118654752f, 0.70710678118654752f, 0.70710678118654752f,
    0.57735026918962576f, 0.57735026918962576f, 0.57735026918962576f, 0.57735026918962576f,
    0.57735026918962576f, 0.57735026918962576f, 0.57735026918962576f, 0.57735026918962576f };

__device__ __forceinline__ float fast_tanh(float x) {
    // tanh(x) = 1 - 2/(exp2(2*log2e*x)+1); exact saturation at +-inf.
    float e = __builtin_amdgcn_exp2f(x * 2.8853900817779268f);
    float r = __builtin_amdgcn_rcpf(e + 1.0f);
    return fmaf(-2.0f, r, 1.0f);
}

// LDS weight layout (floats):
//  W0:[0,64) b0:[64,80) W1:[80,336) b1:[336,352) W2:[352,608) b2:[608,624)
//  W3:[624,880) b3:[880,896) Wout:[896,912) bout:[912]
#define STAGE_WEIGHTS_256()                                                    \
    __shared__ __align__(16) float sw[916];                                    \
    {                                                                          \
        const int t_ = threadIdx.x;                                            \
        if (t_ <  64) sw[      t_] = W0[t_];                                   \
        if (t_ <  16) sw[ 64 + t_] = b0[t_];                                   \
                      sw[ 80 + t_] = W1[t_];                                   \
        if (t_ <  16) sw[336 + t_] = b1[t_];                                   \
                      sw[352 + t_] = W2[t_];                                   \
        if (t_ <  16) sw[608 + t_] = b2[t_];                                   \
                      sw[624 + t_] = W3[t_];                                   \
        if (t_ <  16) sw[880 + t_] = b3[t_];                                   \
        if (t_ <  16) sw[896 + t_] = Wout[t_];                                 \
        if (t_ ==  0) sw[912]     = bout[0];                                   \
        __syncthreads();                                                       \
    }

// sigma(g,p): k-index owned by lane-group g, fragment slot p. Same convention
// builds A (weights), C (biases) and B (inputs); D-chaining reproduces it, so
// any mismatch vs the HW's internal order cancels (verified on HW in R5).
#define SIG(G, P) (((P) < 4) ? 4 * (G) + (P) : 8 + 4 * (G) + ((P) - 4))

// ---------------------------------------------------------------------------
// MFMA flux kernel, sliced k-loop. 3456 blocks x 4 waves. Block b owns
// direction-slice b/864 ({0-3},{4-6},{7-9},{10-12} — uniform trip count per
// block) and 4 voxel-groups of 32 (one per wave). Each wave sets up its
// weight fragments ONCE, then loops its 3-4 directions with the exact R5
// per-pair body (fast_tanh, biases in the MFMA C operand). 13824 waves =
// 13.5/SIMD scheduled -> latency hidden (R7's 3.4 was the regression cause).
__global__ __launch_bounds__(256)
void flux_mfma_kernel(const float* __restrict__ q,
                      const float* __restrict__ W0, const float* __restrict__ b0,
                      const float* __restrict__ W1, const float* __restrict__ b1,
                      const float* __restrict__ W2, const float* __restrict__ b2,
                      const float* __restrict__ W3, const float* __restrict__ b3,
                      const float* __restrict__ Wout, const float* __restrict__ bout,
                      float* __restrict__ ws)
{
    STAGE_WEIGHTS_256()

    const int lane  = threadIdx.x & 63;
    const int wv    = threadIdx.x >> 6;                   // 0..3
    const int g     = lane >> 5;                          // feature-half 0/1
    const int slice = blockIdx.x / (FLUX_BLOCKS / NSLICE);          // 0..3
    const int vgrp  = (blockIdx.x % (FLUX_BLOCKS / NSLICE)) * 4 + wv;
    const int vox   = vgrp * 32 + (lane & 31);

    const int z = vox % NSIDE;
    const int y = (vox / NSIDE) % NSIDE;
    const int x = vox / (NSIDE * NSIDE);
    const int xp = (x == NSIDE - 1) ? 0 : x + 1;
    const int ym = (y == 0) ? NSIDE - 1 : y - 1;
    const int yp = (y == NSIDE - 1) ? 0 : y + 1;
    const int zm = (z == 0) ? NSIDE - 1 : z - 1;
    const int zp = (z == NSIDE - 1) ? 0 : z + 1;

    const float2 own = reinterpret_cast<const float2*>(q)[vox];
    const float o0 = own.x, o1 = own.y;

    // --- loop-invariant fragments (set up once per wave) ---
    const int wr = (lane & 15) * 16;      // A-rows >=16 feed only D regs p>=8,
                                          // which are never read.
    f16x8 aw1, aw2, aw3;
    f32x16 c1, c2, c3;
    #pragma unroll
    for (int p = 0; p < 8; ++p) {
        const int kk = SIG(g, p);
        aw1[p] = (_Float16)sw[ 80 + wr + kk];
        aw2[p] = (_Float16)sw[352 + wr + kk];
        aw3[p] = (_Float16)sw[624 + wr + kk];
        c1[p] = sw[336 + kk];
        c2[p] = sw[608 + kk];
        c3[p] = sw[880 + kk];
    }
    #pragma unroll
    for (int p = 8; p < 16; ++p) { c1[p] = 0.0f; c2[p] = 0.0f; c3[p] = 0.0f; }
    float woutv[8];
    #pragma unroll
    for (int p = 0; p < 8; ++p) woutv[p] = sw[896 + SIG(g, p)];

    const int kb = (slice == 0) ? 0 : (slice == 1) ? 4 : (slice == 2) ? 7 : 10;
    const int ke = (slice == 0) ? 4 : (slice == 1) ? 7 : (slice == 2) ? 10 : 13;

    #pragma unroll 1
    for (int k = kb; k < ke; ++k) {
        // Stop cross-iteration LICM of in-loop LDS reads (R1/R2 spill lesson);
        // register-resident fragments above are unaffected.
        asm volatile("" ::: "memory");

        const int ox = g_ox[k], oy = g_oy[k], oz = g_oz[k];
        const int nx = ox ? xp : x;                       // ox in {0,1}
        const int ny = (oy > 0) ? yp : ((oy < 0) ? ym : y);
        const int nz = (oz > 0) ? zp : ((oz < 0) ? zm : z);
        const float2 nbq = reinterpret_cast<const float2*>(q)[(nx * NSIDE + ny) * NSIDE + nz];
        const float n0 = nbq.x, n1 = nbq.y;

        // --- layer 0 (4 -> 16) on VALU, broadcast LDS float4 reads ---
        f16x8 ba, bb;
        #pragma unroll
        for (int p = 0; p < 8; ++p) {
            const int f = SIG(g, p);
            const float4 w = *reinterpret_cast<const float4*>(&sw[f * 4]);
            const float bbias = sw[64 + f];
            float pa = fmaf(w.x, o0, fmaf(w.y, o1, fmaf(w.z, n0, fmaf(w.w, n1, bbias))));
            float pb = fmaf(w.x, n0, fmaf(w.y, n1, fmaf(w.z, o0, fmaf(w.w, o1, bbias))));
            ba[p] = (_Float16)fast_tanh(pa);
            bb[p] = (_Float16)fast_tanh(pb);
        }

        // --- hidden layers 1..3 on MFMA, biases ride in C (R5 body) ---
        f32x16 da, db;
        da = __builtin_amdgcn_mfma_f32_32x32x16_f16(aw1, ba, c1, 0, 0, 0);
        db = __builtin_amdgcn_mfma_f32_32x32x16_f16(aw1, bb, c1, 0, 0, 0);
        #pragma unroll
        for (int p = 0; p < 8; ++p) {
            ba[p] = (_Float16)fast_tanh(da[p]);
            bb[p] = (_Float16)fast_tanh(db[p]);
        }
        da = __builtin_amdgcn_mfma_f32_32x32x16_f16(aw2, ba, c2, 0, 0, 0);
        db = __builtin_amdgcn_mfma_f32_32x32x16_f16(aw2, bb, c2, 0, 0, 0);
        #pragma unroll
        for (int p = 0; p < 8; ++p) {
            ba[p] = (_Float16)fast_tanh(da[p]);
            bb[p] = (_Float16)fast_tanh(db[p]);
        }
        da = __builtin_amdgcn_mfma_f32_32x32x16_f16(aw3, ba, c3, 0, 0, 0);
        db = __builtin_amdgcn_mfma_f32_32x32x16_f16(aw3, bb, c3, 0, 0, 0);

        // --- output head (16 -> 1): tanh then partial dot; complement from
        //     lane^32. bout cancels in (oa - ob).
        float pa = 0.0f, pb = 0.0f;
        #pragma unroll
        for (int p = 0; p < 8; ++p) {
            pa = fmaf(fast_tanh(da[p]), woutv[p], pa);
            pb = fmaf(fast_tanh(db[p]), woutv[p], pb);
        }
        pa += __shfl_xor(pa, 32);
        pb += __shfl_xor(pb, 32);

        const float tr  = fast_tanh(pa - pb);
        const float fac = (tr < 0.0f) ? o0 : n0;
        if (lane < 32)
            ws[k * NVOX + vox] = tr * fac * g_dinv[k];
    }
}

// ---------------------------------------------------------------------------
// Pass 2: per voxel u, total = sum_k ( f[k][u] - f[k][u - d_k] ).
__global__ __launch_bounds__(256)
void gather_kernel(const float* __restrict__ q,
                   const float* __restrict__ ws,
                   float* __restrict__ out)
{
    const int vox = blockIdx.x * 256 + threadIdx.x;

    const int z = vox % NSIDE;
    const int y = (vox / NSIDE) % NSIDE;
    const int x = vox / (NSIDE * NSIDE);
    const int xm = (x == 0) ? NSIDE - 1 : x - 1;
    const int ym = (y == 0) ? NSIDE - 1 : y - 1;
    const int yp = (y == NSIDE - 1) ? 0 : y + 1;
    const int zm = (z == 0) ? NSIDE - 1 : z - 1;
    const int zp = (z == NSIDE - 1) ? 0 : z + 1;

    float s = 0.0f;
    #pragma unroll
    for (int k = 0; k < NDIR; ++k) {
        const int px = g_ox[k] ? xm : x;
        const int py = (g_oy[k] > 0) ? ym : ((g_oy[k] < 0) ? yp : y);
        const int pz = (g_oz[k] > 0) ? zm : ((g_oz[k] < 0) ? zp : z);
        s += ws[k * NVOX + vox];
        s -= ws[k * NVOX + (px * NSIDE + py) * NSIDE + pz];
    }

    const float2 own = reinterpret_cast<const float2*>(q)[vox];
    float2 r;
    r.x = fmaf(s, SCALE, own.x);
    r.y = own.y;
    reinterpret_cast<float2*>(out)[vox] = r;
}

// ---------------------------------------------------------------------------
// Fallback: Round-3 single-pass scalar kernel (used only if ws is too small).
#define LAYER(WB, INA, INB, OUTA, OUTB)                                        \
    {                                                                          \
        _Pragma("unroll")                                                      \
        for (int i = 0; i < 16; ++i) {                                         \
            float aa = sw[(WB) + 256 + i];                                     \
            float ab = aa;                                                     \
            _Pragma("unroll")                                                  \
            for (int kk = 0; kk < 4; ++kk) {                                   \
                const float4 w = *reinterpret_cast<const float4*>(             \
                    &sw[(WB) + i * 16 + kk * 4]);                              \
                aa = fmaf(w.x, INA[4 * kk + 0], aa);                           \
                aa = fmaf(w.y, INA[4 * kk + 1], aa);                           \
                aa = fmaf(w.z, INA[4 * kk + 2], aa);                           \
                aa = fmaf(w.w, INA[4 * kk + 3], aa);                           \
                ab = fmaf(w.x, INB[4 * kk + 0], ab);                           \
                ab = fmaf(w.y, INB[4 * kk + 1], ab);                           \
                ab = fmaf(w.z, INB[4 * kk + 2], ab);                           \
                ab = fmaf(w.w, INB[4 * kk + 3], ab);                           \
            }                                                                  \
            OUTA[i] = fast_tanh(aa);                                           \
            OUTB[i] = fast_tanh(ab);                                           \
        }                                                                      \
    }

__global__ __launch_bounds__(256)
void automaton_kernel(const float* __restrict__ q,
                      const float* __restrict__ W0, const float* __restrict__ b0,
                      const float* __restrict__ W1, const float* __restrict__ b1,
                      const float* __restrict__ W2, const float* __restrict__ b2,
                      const float* __restrict__ W3, const float* __restrict__ b3,
                      const float* __restrict__ Wout, const float* __restrict__ bout,
                      float* __restrict__ out)
{
    STAGE_WEIGHTS_256()

    const int gid  = blockIdx.x * 256 + threadIdx.x;
    const int vox  = gid >> 1;
    const int half = gid & 1;

    const int z = vox % NSIDE;
    const int y = (vox / NSIDE) % NSIDE;
    const int x = vox / (NSIDE * NSIDE);
    const int xm = (x == 0) ? NSIDE - 1 : x - 1;
    const int xp = (x == NSIDE - 1) ? 0 : x + 1;
    const int ym = (y == 0) ? NSIDE - 1 : y - 1;
    const int yp = (y == NSIDE - 1) ? 0 : y + 1;
    const int zm = (z == 0) ? NSIDE - 1 : z - 1;
    const int zp = (z == NSIDE - 1) ? 0 : z + 1;

    const float2 own = reinterpret_cast<const float2*>(q)[vox];
    const float o0 = own.x, o1 = own.y;

    float sum = 0.0f;
    #pragma unroll 1
    for (int k = half * 13; k < half * 13 + 13; ++k) {
        asm volatile("" ::: "memory");   // block cross-iteration LICM of weight loads
        const int ox = c_ox[k], oy = c_oy[k], oz = c_oz[k];
        const int nx = (ox < 0) ? xm : ((ox > 0) ? xp : x);
        const int ny = (oy < 0) ? ym : ((oy > 0) ? yp : y);
        const int nz = (oz < 0) ? zm : ((oz > 0) ? zp : z);
        const float2 nbq = reinterpret_cast<const float2*>(q)[(nx * NSIDE + ny) * NSIDE + nz];
        const float n0 = nbq.x, n1 = nbq.y;

        float ha[16], hb[16], ta[16], tb[16];
        #pragma unroll
        for (int i = 0; i < 16; ++i) {
            const float4 w = *reinterpret_cast<const float4*>(&sw[i * 4]);
            const float bbias = sw[64 + i];
            float pa = fmaf(w.x, o0, fmaf(w.y, o1, fmaf(w.z, n0, fmaf(w.w, n1, bbias))));
            float pb = fmaf(w.x, n0, fmaf(w.y, n1, fmaf(w.z, o0, fmaf(w.w, o1, bbias))));
            ha[i] = fast_tanh(pa);
            hb[i] = fast_tanh(pb);
        }
        LAYER(80,  ha, hb, ta, tb)
        LAYER(352, ta, tb, ha, hb)
        LAYER(624, ha, hb, ta, tb)
        float oa = sw[912], ob = sw[912];
        #pragma unroll
        for (int kk = 0; kk < 4; ++kk) {
            const float4 w = *reinterpret_cast<const float4*>(&sw[896 + kk * 4]);
            oa = fmaf(w.x, ta[4 * kk + 0], oa);
            oa = fmaf(w.y, ta[4 * kk + 1], oa);
            oa = fmaf(w.z, ta[4 * kk + 2], oa);
            oa = fmaf(w.w, ta[4 * kk + 3], oa);
            ob = fmaf(w.x, tb[4 * kk + 0], ob);
            ob = fmaf(w.y, tb[4 * kk + 1], ob);
            ob = fmaf(w.z, tb[4 * kk + 2], ob);
            ob = fmaf(w.w, tb[4 * kk + 3], ob);
        }
        const float tr  = fast_tanh(oa - ob);
        const float fac = (tr < 0.0f) ? o0 : n0;
        sum = fmaf(tr * fac, c_dinv[k], sum);
    }

    sum += __shfl_xor(sum, 1);
    if (half == 0) {
        float2 r;
        r.x = fmaf(sum, SCALE, o0);
        r.y = o1;
        reinterpret_cast<float2*>(out)[vox] = r;
    }
}

extern "C" void kernel_launch(void* const* d_in, const int* in_sizes, int n_in,
                              void* d_out, int out_size, void* d_ws, size_t ws_size,
                              hipStream_t stream) {
    const float* q    = (const float*)d_in[0];
    const float* W0   = (const float*)d_in[1];
    const float* b0   = (const float*)d_in[2];
    const float* W1   = (const float*)d_in[3];
    const float* b1   = (const float*)d_in[4];
    const float* W2   = (const float*)d_in[5];
    const float* b2   = (const float*)d_in[6];
    const float* W3   = (const float*)d_in[7];
    const float* b3   = (const float*)d_in[8];
    const float* Wout = (const float*)d_in[9];
    const float* bout = (const float*)d_in[10];
    float* out = (float*)d_out;

    const size_t ws_needed = (size_t)NDIR * NVOX * sizeof(float);  // 5.75 MB
    if (ws_size >= ws_needed) {
        float* ws = (float*)d_ws;
        flux_mfma_kernel<<<dim3(FLUX_BLOCKS), dim3(256), 0, stream>>>(
            q, W0, b0, W1, b1, W2, b2, W3, b3, Wout, bout, ws);
        gather_kernel<<<dim3(NVOX / 256), dim3(256), 0, stream>>>(q, ws, out);
    } else {
        automaton_kernel<<<dim3(NVOX * 2 / 256), dim3(256), 0, stream>>>(
            q, W0, b0, W1, b1, W2, b2, W3, b3, Wout, bout, out);
    }
}